// Round 9
// baseline (144.548 us; speedup 1.0000x reference)
//
#include <hip/hip_runtime.h>
#include <hip/hip_bf16.h>

#define B_     4
#define V_IN   12500
#define V_OUT  50000
#define C_IN   64
#define C_OUT  32
#define SPIRAL 9
#define K_NNZ  3
#define ROWS   (B_ * V_OUT)       // 200000
#define KDIM   (SPIRAL * C_IN)    // 576
#define KSTEPS (KDIM / 32)        // 18 (16x16x32 MFMA)
#define WFRAG_ELEMS (KSTEPS * 2 * 64 * 8)  // 18432 bf16 = 36864 B

#define GROUPS_PER_B (V_OUT / 16) // 3125 16-row groups per batch (k1)
#define G1           2048         // k1 blocks (+1 W-prep); 256 per XCD
#define TILES_PER_B  782          // 781 full 64-row tiles + one 16-row tail (k2)
#define G2           1024         // k2: 128 blocks per (b,ch) XCD; 4 blocks/CU (36KB LDS)
#define TSTEP        128          // tiles stride = blocks per partition
#define G3           2048         // combine blocks (XCD-aligned to batch)

#define SLOTB        1024         // bytes per gather slot (64 lanes * 16 B)
#define BUFB         (SPIRAL * SLOTB)      // 9216 B per wave (single buffer)

typedef __attribute__((ext_vector_type(8))) short short8_t;      // 8 bf16 (4 VGPRs)
typedef __attribute__((ext_vector_type(4))) float floatx4;       // 4 fp32 acc
typedef __attribute__((ext_vector_type(4))) unsigned short u16x4;

__device__ __forceinline__ unsigned short f32_to_bf16(float f) {
    unsigned int u = __float_as_uint(f);
    unsigned int r = u + 0x7fffu + ((u >> 16) & 1u);   // round-to-nearest-even
    return (unsigned short)(r >> 16);
}

// Async global->LDS, 16B per lane. LDS dest = base + lane*16 (linear, HW rule).
__device__ __forceinline__ void glds16(const void* g, void* l) {
    __builtin_amdgcn_global_load_lds(
        (const __attribute__((address_space(1))) unsigned int*)g,
        (__attribute__((address_space(3))) unsigned int*)l, 16, 0, 0);
}

// Kernel 1: up[b,v,c] = sum_k x[b,up_idx[v,k],c]*up_val[v,k] -> bf16 planes
// plane[ch][b][v][32]. R9: back to FULL-row processing (one idx/val read
// serves both planes -- R8's half-split doubled that traffic class), with
// VECTORIZED idx/val (int4+float4: 6 scalar loads -> 2 vector loads per
// row; guard on last row for OOB) and NONTEMPORAL stores (keep the x
// working set resident in L2 for its ~12x gather reuse -- R8's cached
// stores let 3.2 MB of dirty plane lines thrash it).
// XCD pair 2b/2b+1 shares batch b (x[b] gathers L2/L3-local).
// Block G1: rearrange weight (576x32 fp32) into MFMA fragment order (bf16):
//   w_frag[((kstep*2+ntile)*64+lane)*8+j] = W[kstep*32+(lane>>4)*8+j][ntile*16+(lane&15)]
__global__ __launch_bounds__(256) void upsample_kernel(
    const float* __restrict__ x,
    const int* __restrict__ up_idx,
    const float* __restrict__ up_val,
    const float* __restrict__ weight,
    unsigned short* __restrict__ up_planes,
    unsigned short* __restrict__ w_frag)
{
    int tid = threadIdx.x;
    if (blockIdx.x == G1) {
        for (int idx = tid; idx < WFRAG_ELEMS; idx += 256) {
            int j     = idx & 7;
            int lane  = (idx >> 3) & 63;
            int ntile = (idx >> 9) & 1;
            int kstep = idx >> 10;
            int k = kstep * 32 + (lane >> 4) * 8 + j;
            int n = ntile * 16 + (lane & 15);
            w_frag[idx] = f32_to_bf16(weight[k * C_OUT + n]);
        }
        return;
    }
    int xcd = blockIdx.x & 7;
    int b   = xcd >> 1;                     // batch owned by this XCD pair
    int h   = xcd & 1;
    int j   = blockIdx.x >> 3;              // [0, 256)
    int lane16 = tid & 15;                  // 4 channels each (float4)
    int sub    = tid >> 4;                  // row within 16-row group
    int half   = lane16 >> 3;               // channel plane (c>=32)
    int c8     = lane16 & 7;                // 4-short chunk within plane row

    const float* xb = x + (size_t)b * V_IN * C_IN;
    unsigned short* plane = up_planes
        + ((size_t)(half * B_ + b)) * V_OUT * 32 + (size_t)c8 * 4;

    for (int gl = h + 2 * j; gl < GROUPS_PER_B; gl += 512) {
        int v = gl * 16 + sub;              // local row within batch b
        int u0, u1, u2; float w0, w1, w2;
        if (v < V_OUT - 1) {
            int4   iv = *(const int4*)(up_idx + (size_t)v * K_NNZ);
            float4 vv = *(const float4*)(up_val + (size_t)v * K_NNZ);
            u0 = iv.x; u1 = iv.y; u2 = iv.z;
            w0 = vv.x; w1 = vv.y; w2 = vv.z;
        } else {                            // last row: scalar (no OOB)
            const int*   ui = up_idx + (size_t)v * K_NNZ;
            const float* uv = up_val + (size_t)v * K_NNZ;
            u0 = ui[0]; u1 = ui[1]; u2 = ui[2];
            w0 = uv[0]; w1 = uv[1]; w2 = uv[2];
        }
        float4 x0 = *((const float4*)(xb + (size_t)u0 * C_IN) + lane16);
        float4 x1 = *((const float4*)(xb + (size_t)u1 * C_IN) + lane16);
        float4 x2 = *((const float4*)(xb + (size_t)u2 * C_IN) + lane16);
        float a0 = w0 * x0.x + w1 * x1.x + w2 * x2.x;
        float a1 = w0 * x0.y + w1 * x1.y + w2 * x2.y;
        float a2 = w0 * x0.z + w1 * x1.z + w2 * x2.z;
        float a3 = w0 * x0.w + w1 * x1.w + w2 * x2.w;
        u16x4 o;
        o[0] = f32_to_bf16(a0); o[1] = f32_to_bf16(a1);
        o[2] = f32_to_bf16(a2); o[3] = f32_to_bf16(a3);
        __builtin_nontemporal_store(o, (u16x4*)(plane + (size_t)v * 32));
    }
}

// Kernel 2: partial GEMM over one K-half. XCD xcd = b*2+ch. UNCHANGED from
// R8 (141.3us round): single 36KB buffer, 4 blocks/CU, counted vmcnt(5):
// body order compute(t) -> glds(t+1) -> idx(t+2) -> store(t); loop-top
// vmcnt(5) leaves only idx(t+1)(3) + store(t-1)(2) in flight -> glds(t)
// retired (issued a full iter earlier, wait ~free), stores never drained.
__global__ __launch_bounds__(256, 4) void gemm_half_kernel(
    const unsigned short* __restrict__ up_planes,
    const int* __restrict__ spiral,
    const unsigned short* __restrict__ w_frag,
    float* __restrict__ p0,
    float* __restrict__ out)
{
    __shared__ unsigned short gbuf[4 * SPIRAL * 512];   // 4 waves * 9 KB

    int tid  = threadIdx.x;
    int wave = tid >> 6;
    int lane = tid & 63;
    int m    = lane & 15;
    int quad = lane >> 4;
    int r    = lane >> 2;          // gather row within 16-row wave tile
    int q    = lane & 3;           // gather sector lane
    int swz  = q ^ ((r >> 1) & 3); // sector actually fetched by this lane
    int fm   = (m >> 1) & 3;       // read-side swizzle for row m

    int xcd = blockIdx.x & 7;
    int b   = xcd >> 1;
    int ch  = xcd & 1;
    int j   = blockIdx.x >> 3;              // [0, TSTEP)

    // W fragments for this half -> registers (loop-invariant, 72 VGPR).
    short8_t w[2 * SPIRAL];
#pragma unroll
    for (int f = 0; f < 2 * SPIRAL; f++) {
        int s  = f >> 1;
        int nt = f & 1;
        w[f] = *(const short8_t*)(w_frag + (((size_t)(2 * s + ch) * 2 + nt) * 64 + lane) * 8);
    }

    const unsigned short* upb = up_planes + ((size_t)(ch * B_ + b)) * V_OUT * 32;
    float* dst = (ch ? out : p0) + (size_t)b * V_OUT * C_OUT;
    char* mybuf = (char*)gbuf + (size_t)wave * BUFB;

    int nspv[SPIRAL];
    // ---- prologue: idx(t0) -> glds(t0) -> vmcnt(0) -> idx(t1) ----
    {
        int v0 = j * 64 + wave * 16 + r;
        v0 = v0 < V_OUT ? v0 : 0;
        const int* p = spiral + (size_t)v0 * SPIRAL;
        int4 ia = *(const int4*)p;
        int4 ib = *(const int4*)(p + 4);
        int  ic = p[8];
        nspv[0]=ia.x; nspv[1]=ia.y; nspv[2]=ia.z; nspv[3]=ia.w;
        nspv[4]=ib.x; nspv[5]=ib.y; nspv[6]=ib.z; nspv[7]=ib.w; nspv[8]=ic;
        __builtin_amdgcn_sched_barrier(0);
#pragma unroll
        for (int s = 0; s < SPIRAL; s++) {
            const void* ga = (const char*)upb + (size_t)nspv[s] * 64 + swz * 16;
            glds16(ga, mybuf + s * SLOTB);
        }
        asm volatile("s_waitcnt vmcnt(0)" ::: "memory");
        __builtin_amdgcn_sched_barrier(0);
        int v1 = (j + TSTEP) * 64 + wave * 16 + r;
        v1 = v1 < V_OUT ? v1 : 0;
        const int* pn = spiral + (size_t)v1 * SPIRAL;
        int4 ja = *(const int4*)pn;
        int4 jb = *(const int4*)(pn + 4);
        int  jc = pn[8];
        nspv[0]=ja.x; nspv[1]=ja.y; nspv[2]=ja.z; nspv[3]=ja.w;
        nspv[4]=jb.x; nspv[5]=jb.y; nspv[6]=jb.z; nspv[7]=jb.w; nspv[8]=jc;
    }

    for (int tl = j; tl < TILES_PER_B; tl += TSTEP) {
        // 0) wait: only the 5 youngest VMEM ops (idx(t+1)=3, store(t-1)=2)
        //    may remain in flight -> glds(t) complete.
        asm volatile("s_waitcnt vmcnt(5)" ::: "memory");
        __builtin_amdgcn_sched_barrier(0);

        // 1) compute tile t from the single buffer.
        floatx4 acc0 = {0.f, 0.f, 0.f, 0.f};
        floatx4 acc1 = {0.f, 0.f, 0.f, 0.f};
#pragma unroll
        for (int s = 0; s < SPIRAL; s++) {
            short8_t g = *(const short8_t*)(mybuf + s * SLOTB + m * 64 + ((quad ^ fm) * 16));
            acc0 = __builtin_amdgcn_mfma_f32_16x16x32_bf16(w[2 * s + 0], g, acc0, 0, 0, 0);
            acc1 = __builtin_amdgcn_mfma_f32_16x16x32_bf16(w[2 * s + 1], g, acc1, 0, 0, 0);
        }
        __builtin_amdgcn_sched_barrier(0);   // ds_reads issued before glds below

        int tln = tl + TSTEP;
        if (tln < TILES_PER_B) {             // block-uniform
            // 2) glds(t+1) into the same buffer (addresses loaded a full
            //    iteration ago -> compiler's idx-wait is free; ds_reads
            //    above already issued, glds data returns later).
#pragma unroll
            for (int s = 0; s < SPIRAL; s++) {
                const void* ga = (const char*)upb + (size_t)nspv[s] * 64 + swz * 16;
                glds16(ga, mybuf + s * SLOTB);
            }
            __builtin_amdgcn_sched_barrier(0);
            // 3) idx(t+2) prefetch (plain cached; 3 VMEM ops).
            int v2 = (tln + TSTEP) * 64 + wave * 16 + r;
            v2 = (v2 < V_OUT) ? v2 : 0;
            const int* pn = spiral + (size_t)v2 * SPIRAL;
            int4 ja = *(const int4*)pn;
            int4 jb = *(const int4*)(pn + 4);
            int  jc = pn[8];
            nspv[0]=ja.x; nspv[1]=ja.y; nspv[2]=ja.z; nspv[3]=ja.w;
            nspv[4]=jb.x; nspv[5]=jb.y; nspv[6]=jb.z; nspv[7]=jb.w; nspv[8]=jc;
            __builtin_amdgcn_sched_barrier(0);
        }

        // 4) store(t) -- youngest VMEM ops; never explicitly waited.
        int vr = tl * 64 + wave * 16 + m;
        if (vr < V_OUT) {
            float* op = dst + (size_t)vr * C_OUT;
            __builtin_nontemporal_store(acc0, (floatx4*)(op + quad * 4));
            __builtin_nontemporal_store(acc1, (floatx4*)(op + 16 + quad * 4));
        }
    }
}

// Kernel 3: out = relu(out + p0 + bias). R9: XCD-aligned -- blocks on XCD
// pair 2b/2b+1 combine batch b, so p0[b] (dirty in XCD 2b+0's L2 from k2)
// is same-die; p0 read is PLAIN cached to exploit hits. out read/write
// stay nontemporal (pure stream).
__global__ __launch_bounds__(256) void combine_kernel(
    const float* __restrict__ p0,
    const float* __restrict__ bias,
    float* __restrict__ out)
{
    int xcd = blockIdx.x & 7;
    int b   = xcd >> 1;
    int hj  = (blockIdx.x >> 3) * 2 + (xcd & 1);     // [0, 512) within batch
    const size_t perB = (size_t)V_OUT * (C_OUT / 4); // 400000 float4 units
    const float* p0b = p0 + (size_t)b * V_OUT * C_OUT;
    float* outb = out + (size_t)b * V_OUT * C_OUT;

    for (size_t i = (size_t)hj * 256 + threadIdx.x; i < perB; i += 512 * 256) {
        floatx4 a = *((const floatx4*)p0b + i);      // cached: L2-local dirty
        floatx4 c = __builtin_nontemporal_load((const floatx4*)outb + i);
        floatx4 bb = *((const floatx4*)bias + (i & 7));
        floatx4 rr = a + c + bb;
        rr[0] = fmaxf(rr[0], 0.f); rr[1] = fmaxf(rr[1], 0.f);
        rr[2] = fmaxf(rr[2], 0.f); rr[3] = fmaxf(rr[3], 0.f);
        __builtin_nontemporal_store(rr, (floatx4*)outb + i);
    }
}

extern "C" void kernel_launch(void* const* d_in, const int* in_sizes, int n_in,
                              void* d_out, int out_size, void* d_ws, size_t ws_size,
                              hipStream_t stream) {
    const float* x      = (const float*)d_in[0];
    const int*   spiral = (const int*)d_in[1];
    const int*   up_idx = (const int*)d_in[2];
    const float* up_val = (const float*)d_in[3];
    const float* weight = (const float*)d_in[4];
    const float* bias   = (const float*)d_in[5];
    float* out = (float*)d_out;

    // ws layout: planes (25.6 MB) | w_frag (36 KB) | p0 (25.6 MB) = 51.3 MB
    unsigned short* up_ws  = (unsigned short*)d_ws;
    unsigned short* w_frag = up_ws + (size_t)2 * B_ * V_OUT * 32;
    float* p0 = (float*)(w_frag + WFRAG_ELEMS);

    upsample_kernel<<<G1 + 1, 256, 0, stream>>>(x, up_idx, up_val, weight, up_ws, w_frag);
    gemm_half_kernel<<<G2, 256, 0, stream>>>(up_ws, spiral, w_frag, p0, out);
    combine_kernel<<<G3, 256, 0, stream>>>(p0, bias, out);
}